// Round 4
// baseline (418.277 us; speedup 1.0000x reference)
//
#include <hip/hip_runtime.h>
#include <hip/hip_bf16.h>

typedef __hip_bfloat16 bf16;
typedef __attribute__((ext_vector_type(8))) short short8;
typedef __attribute__((ext_vector_type(4))) float f32x4;

#define S_LEN 2048
#define BATCH 2
#define M_TOT 4096   // BATCH*S_LEN
#define HID 2048
#define NH 32
#define NKV 8
#define HD 64
#define KVD 512      // NKV*HD
#define PSTR 72      // P-tile LDS stride (bf16)

#define MFMA16(a, b, c) __builtin_amdgcn_mfma_f32_16x16x32_bf16(a, b, c, 0, 0, 0)

__device__ __forceinline__ void gload_lds16(const bf16* g, bf16* l) {
    __builtin_amdgcn_global_load_lds((const __attribute__((address_space(1))) void*)g,
                                     (__attribute__((address_space(3))) void*)l,
                                     16, 0, 0);
}

// ---------------- cast fp32 -> bf16, vectorized ----------------
__global__ void cast_kernel(const float* __restrict__ src, bf16* __restrict__ dst, int n8) {
    int stride = gridDim.x * blockDim.x;
    for (int i = blockIdx.x * blockDim.x + threadIdx.x; i < n8; i += stride) {
        const float4* s = (const float4*)(src + (size_t)i * 8);
        float4 a = s[0], b = s[1];
        bf16 tmp[8];
        tmp[0] = __float2bfloat16(a.x); tmp[1] = __float2bfloat16(a.y);
        tmp[2] = __float2bfloat16(a.z); tmp[3] = __float2bfloat16(a.w);
        tmp[4] = __float2bfloat16(b.x); tmp[5] = __float2bfloat16(b.y);
        tmp[6] = __float2bfloat16(b.z); tmp[7] = __float2bfloat16(b.w);
        *(short8*)(dst + (size_t)i * 8) = *(short8*)tmp;
    }
}

// ---------------- RoPE tables: [S][32] cos, sin (fp32) ----------------
__global__ void rope_tables_kernel(float* __restrict__ cosb, float* __restrict__ sinb) {
    int idx = blockIdx.x * blockDim.x + threadIdx.x;
    if (idx >= S_LEN * 32) return;
    int s = idx >> 5, d = idx & 31;
    float freq = powf(10000.0f, -(float)(2 * d) / 64.0f);
    float ang = (float)s * freq;
    cosb[idx] = cosf(ang);
    sinb[idx] = sinf(ang);
}

// ---------------- RoPE apply, in place on bf16 (M_TOT, nh*64) ----------------
__global__ void rope_kernel(bf16* __restrict__ buf, const float* __restrict__ cosb,
                            const float* __restrict__ sinb, int nh, int npairs) {
    int stride = gridDim.x * blockDim.x;
    int hw = nh * 32;
    for (int idx = blockIdx.x * blockDim.x + threadIdx.x; idx < npairs; idx += stride) {
        int m = idx / hw;
        int r = idx - m * hw;
        int h = r >> 5, d = r & 31;
        int s = m & (S_LEN - 1);
        float c = cosb[s * 32 + d], sn = sinb[s * 32 + d];
        bf16* p = buf + (size_t)m * (nh * HD) + h * HD + 2 * d;
        __hip_bfloat162 xv = *(__hip_bfloat162*)p;
        float xe = __bfloat162float(xv.x), xo = __bfloat162float(xv.y);
        __hip_bfloat162 ov;
        ov.x = __float2bfloat16(xe * c - xo * sn);
        ov.y = __float2bfloat16(xe * sn + xo * c);
        *(__hip_bfloat162*)p = ov;
    }
}

// ---------------- GEMM core: 128x128 tile, BK=64, swizzled LDS (m97 class) ----
// LDS [128][64] linear-by-chunk; logical slot s of row r stored at phys s^(r&7)
// via pre-swizzled GLOBAL source (gload_lds dest must be linear).
__device__ __forceinline__ void gemm_core(const bf16* __restrict__ A,
                                          const bf16* __restrict__ W,
                                          int K, int m0, int n0,
                                          bf16* As, bf16* Bs,
                                          f32x4 acc[4][4]) {
    int tid = threadIdx.x;
    int lane = tid & 63, wid = tid >> 6;
    int wr = wid >> 1, wc = wid & 1;
    int lhi = lane >> 4, llo = lane & 15;
    const bf16* gA[4]; const bf16* gB[4];
    bf16 *lA[4], *lB[4];
    #pragma unroll
    for (int q = 0; q < 4; q++) {
        int c = tid + 256 * q;
        int row = c >> 3;
        int sl = (c & 7) ^ (row & 7);     // pre-swizzled source slot
        gA[q] = A + (size_t)(m0 + row) * K + sl * 8;
        gB[q] = W + (size_t)(n0 + row) * K + sl * 8;
        lA[q] = As + c * 8;
        lB[q] = Bs + c * 8;
    }
    for (int k0 = 0; k0 < K; k0 += 64) {
        #pragma unroll
        for (int q = 0; q < 4; q++) {
            gload_lds16(gA[q] + k0, lA[q]);
            gload_lds16(gB[q] + k0, lB[q]);
        }
        __syncthreads();
        short8 af[4][2], bfr[4][2];
        #pragma unroll
        for (int i = 0; i < 4; i++) {
            int row = wr * 64 + i * 16 + llo;
            int x = row & 7;
            af[i][0] = *(const short8*)(As + row * 64 + ((lhi ^ x) * 8));
            af[i][1] = *(const short8*)(As + row * 64 + (((4 + lhi) ^ x) * 8));
        }
        #pragma unroll
        for (int j = 0; j < 4; j++) {
            int row = wc * 64 + j * 16 + llo;
            int x = row & 7;
            bfr[j][0] = *(const short8*)(Bs + row * 64 + ((lhi ^ x) * 8));
            bfr[j][1] = *(const short8*)(Bs + row * 64 + (((4 + lhi) ^ x) * 8));
        }
        #pragma unroll
        for (int i = 0; i < 4; i++)
            #pragma unroll
            for (int j = 0; j < 4; j++) {
                acc[i][j] = MFMA16(af[i][0], bfr[j][0], acc[i][j]);
                acc[i][j] = MFMA16(af[i][1], bfr[j][1], acc[i][j]);
            }
        __syncthreads();
    }
}

// ---------------- fused QKV projection ----------------
__global__ __launch_bounds__(256) void gemm_qkv_kernel(
        const bf16* __restrict__ xb,
        const bf16* __restrict__ wq, const bf16* __restrict__ wk, const bf16* __restrict__ wv,
        bf16* __restrict__ qb, bf16* __restrict__ kb, bf16* __restrict__ vtb) {
    __shared__ bf16 As[128 * 64];
    __shared__ bf16 Bs[128 * 64];
    int by = blockIdx.y;
    const bf16* W; bf16* Cb; int n0, ldc, mode;
    if (by < 16)      { W = wq; Cb = qb;  n0 = by * 128;        ldc = 2048; mode = 0; }
    else if (by < 20) { W = wk; Cb = kb;  n0 = (by - 16) * 128; ldc = 512;  mode = 0; }
    else              { W = wv; Cb = vtb; n0 = (by - 20) * 128; ldc = 0;    mode = 1; }
    int m0 = blockIdx.x * 128;

    f32x4 acc[4][4] = {};
    gemm_core(xb, W, HID, m0, n0, As, Bs, acc);

    int lane = threadIdx.x & 63, wid = threadIdx.x >> 6;
    int wr = wid >> 1, wc = wid & 1;
    int lhi = lane >> 4, llo = lane & 15;
    #pragma unroll
    for (int i = 0; i < 4; i++)
        #pragma unroll
        for (int j = 0; j < 4; j++) {
            int col = wc * 64 + j * 16 + llo;
            #pragma unroll
            for (int r = 0; r < 4; r++) {
                int row = wr * 64 + i * 16 + lhi * 4 + r;
                int m = m0 + row;
                float v = acc[i][j][r];
                if (mode == 0) {
                    Cb[(size_t)m * ldc + n0 + col] = __float2bfloat16(v);
                } else {
                    int bb = m >> 11, ss = m & 2047;
                    Cb[((size_t)(bb * 512 + n0 + col)) * S_LEN + ss] = __float2bfloat16(v);
                }
            }
        }
}

// ---------------- output projection: fp32 out ----------------
__global__ __launch_bounds__(256) void gemm_out_kernel(
        const bf16* __restrict__ attnb, const bf16* __restrict__ wob,
        float* __restrict__ out) {
    __shared__ bf16 As[128 * 64];
    __shared__ bf16 Bs[128 * 64];
    int m0 = blockIdx.x * 128;
    int n0 = blockIdx.y * 128;
    f32x4 acc[4][4] = {};
    gemm_core(attnb, wob, HID, m0, n0, As, Bs, acc);

    int lane = threadIdx.x & 63, wid = threadIdx.x >> 6;
    int wr = wid >> 1, wc = wid & 1;
    int lhi = lane >> 4, llo = lane & 15;
    #pragma unroll
    for (int i = 0; i < 4; i++)
        #pragma unroll
        for (int j = 0; j < 4; j++) {
            int col = wc * 64 + j * 16 + llo;
            #pragma unroll
            for (int r = 0; r < 4; r++) {
                int row = wr * 64 + i * 16 + lhi * 4 + r;
                out[(size_t)(m0 + row) * HID + n0 + col] = acc[i][j][r];
            }
        }
}

// ---------------- flash attention: softmax + PV for one 16x64 wave-update ----
template<bool MASKED>
__device__ __forceinline__ void sm_pv(const f32x4 z[4], int t0, int q0w, int lhi, int llo,
                                      bf16* pl, const short8 vf0[4], const short8 vf1[4],
                                      f32x4 acc[4], float psum[4]) {
    #pragma unroll
    for (int cb = 0; cb < 4; cb++)
        #pragma unroll
        for (int r = 0; r < 4; r++) {
            float p = __expf(z[cb][r] * 0.125f);
            if (MASKED)
                p = (t0 + cb * 16 + llo <= q0w + lhi * 4 + r) ? p : 0.f;
            psum[r] += p;
            pl[(lhi * 4 + r) * PSTR + cb * 16 + llo] = __float2bfloat16(p);
        }
    short8 p0 = *(const short8*)(pl + llo * PSTR + lhi * 8);
    short8 p1 = *(const short8*)(pl + llo * PSTR + 32 + lhi * 8);
    #pragma unroll
    for (int jb = 0; jb < 4; jb++) {
        acc[jb] = MFMA16(p0, vf0[jb], acc[jb]);
        acc[jb] = MFMA16(p1, vf1[jb], acc[jb]);
    }
}

// grid: (16, B*NH). Block i: q-tiles jA=i, jB=31-i; kv tiles 0..jB staged once.
// Single LDS K/V buffer; reg-staged prefetch of tile t+1 hidden under compute.
__global__ __launch_bounds__(256, 4) void flash_kernel(
        const bf16* __restrict__ qb, const bf16* __restrict__ kb,
        const bf16* __restrict__ vtb, bf16* __restrict__ attnb) {
    __shared__ bf16 Ks[64 * 64];
    __shared__ bf16 Vs[64 * 64];
    __shared__ bf16 Pl[4][2][16 * PSTR];
    int bh = blockIdx.y;
    int b = bh >> 5, h = bh & 31;
    int kvh = h >> 2;
    int jA = blockIdx.x, jB = 31 - jA;
    int tid = threadIdx.x;
    int wid = tid >> 6, lane = tid & 63;
    int lhi = lane >> 4, llo = lane & 15;
    int qA0 = jA * 64 + wid * 16;
    int qB0 = jB * 64 + wid * 16;

    const bf16* qbase = qb + (size_t)(b * S_LEN) * (NH * HD) + h * HD;
    short8 qfA0 = *(const short8*)(qbase + (size_t)(qA0 + llo) * (NH * HD) + lhi * 8);
    short8 qfA1 = *(const short8*)(qbase + (size_t)(qA0 + llo) * (NH * HD) + 32 + lhi * 8);
    short8 qfB0 = *(const short8*)(qbase + (size_t)(qB0 + llo) * (NH * HD) + lhi * 8);
    short8 qfB1 = *(const short8*)(qbase + (size_t)(qB0 + llo) * (NH * HD) + 32 + lhi * 8);

    const bf16* Kg = kb + (size_t)(b * S_LEN) * KVD + kvh * HD;
    const bf16* Vg = vtb + (size_t)(b * 512 + kvh * 64) * S_LEN;

    // staging: chunk c -> row c>>3, linear global slot c&7; LDS write swizzled
    int c0 = tid, c1 = tid + 256;
    int r0 = c0 >> 3, s0 = (c0 & 7) * 8;
    int r1 = c1 >> 3, s1 = (c1 & 7) * 8;
    bf16* wK0 = Ks + r0 * 64 + (((c0 & 7) ^ (r0 & 7)) * 8);
    bf16* wK1 = Ks + r1 * 64 + (((c1 & 7) ^ (r1 & 7)) * 8);
    bf16* wV0 = Vs + r0 * 64 + (((c0 & 7) ^ (r0 & 7)) * 8);
    bf16* wV1 = Vs + r1 * 64 + (((c1 & 7) ^ (r1 & 7)) * 8);

    f32x4 accA[4] = {}, accB[4] = {};
    float psumA[4] = {0.f, 0.f, 0.f, 0.f}, psumB[4] = {0.f, 0.f, 0.f, 0.f};
    bf16* plA = &Pl[wid][0][0];
    bf16* plB = &Pl[wid][1][0];

    // prologue: stage tile 0
    {
        uint4 a = *(const uint4*)(Kg + (size_t)r0 * KVD + s0);
        uint4 bq = *(const uint4*)(Kg + (size_t)r1 * KVD + s1);
        uint4 cq = *(const uint4*)(Vg + (size_t)r0 * S_LEN + s0);
        uint4 dq = *(const uint4*)(Vg + (size_t)r1 * S_LEN + s1);
        *(uint4*)wK0 = a;  *(uint4*)wK1 = bq;
        *(uint4*)wV0 = cq; *(uint4*)wV1 = dq;
        asm volatile("s_waitcnt lgkmcnt(0)" ::: "memory");
        __builtin_amdgcn_s_barrier();
    }

    for (int t = 0; t <= jB; ++t) {
        int t0 = t * 64;
        bool pf = (t < jB);
        uint4 nk0, nk1, nv0, nv1;
        if (pf) {   // prefetch tile t+1 into regs; latency hidden under compute
            int tn = t0 + 64;
            nk0 = *(const uint4*)(Kg + (size_t)(tn + r0) * KVD + s0);
            nk1 = *(const uint4*)(Kg + (size_t)(tn + r1) * KVD + s1);
            nv0 = *(const uint4*)(Vg + (size_t)r0 * S_LEN + tn + s0);
            nv1 = *(const uint4*)(Vg + (size_t)r1 * S_LEN + tn + s1);
        }
        __builtin_amdgcn_sched_barrier(0);   // keep prefetch issue above compute

        bool doA = (t <= jA);
        // ---- K frags + QK^T for both q-tiles ----
        f32x4 zA[4], zB[4];
        #pragma unroll
        for (int cb = 0; cb < 4; cb++) {
            int row = cb * 16 + llo;
            int x = row & 7;
            short8 k0 = *(const short8*)(Ks + row * 64 + ((lhi ^ x) * 8));
            short8 k1 = *(const short8*)(Ks + row * 64 + (((lhi + 4) ^ x) * 8));
            f32x4 z = {0.f, 0.f, 0.f, 0.f};
            z = MFMA16(qfB0, k0, z);
            z = MFMA16(qfB1, k1, z);
            zB[cb] = z;
            if (doA) {
                f32x4 y = {0.f, 0.f, 0.f, 0.f};
                y = MFMA16(qfA0, k0, y);
                y = MFMA16(qfA1, k1, y);
                zA[cb] = y;
            }
        }
        // ---- V frags (shared by A and B) ----
        short8 vf0[4], vf1[4];
        #pragma unroll
        for (int jb = 0; jb < 4; jb++) {
            int row = jb * 16 + llo;
            int x = row & 7;
            vf0[jb] = *(const short8*)(Vs + row * 64 + ((lhi ^ x) * 8));
            vf1[jb] = *(const short8*)(Vs + row * 64 + (((lhi + 4) ^ x) * 8));
        }
        // ---- softmax + PV (mask only on diagonal tiles; wave-uniform) ----
        if (t == jB) sm_pv<true >(zB, t0, qB0, lhi, llo, plB, vf0, vf1, accB, psumB);
        else         sm_pv<false>(zB, t0, qB0, lhi, llo, plB, vf0, vf1, accB, psumB);
        if (doA) {
            if (t == jA) sm_pv<true >(zA, t0, qA0, lhi, llo, plA, vf0, vf1, accA, psumA);
            else         sm_pv<false>(zA, t0, qA0, lhi, llo, plA, vf0, vf1, accA, psumA);
        }
        __builtin_amdgcn_s_barrier();        // all waves done reading Ks/Vs
        if (pf) {
            *(uint4*)wK0 = nk0; *(uint4*)wK1 = nk1;
            *(uint4*)wV0 = nv0; *(uint4*)wV1 = nv1;
        }
        asm volatile("s_waitcnt lgkmcnt(0)" ::: "memory");
        __builtin_amdgcn_s_barrier();        // new tile visible to all
    }

    // ---- final denominator reductions + epilogues ----
    #pragma unroll
    for (int off = 1; off < 16; off <<= 1)
        #pragma unroll
        for (int r = 0; r < 4; r++) {
            psumA[r] += __shfl_xor(psumA[r], off, 64);
            psumB[r] += __shfl_xor(psumB[r], off, 64);
        }
    float invA[4], invB[4];
    #pragma unroll
    for (int r = 0; r < 4; r++) {
        invA[r] = 1.0f / psumA[r];
        invB[r] = 1.0f / psumB[r];
    }
    size_t obaseA = ((size_t)(b * S_LEN) + qA0) * (NH * HD) + h * HD;
    size_t obaseB = ((size_t)(b * S_LEN) + qB0) * (NH * HD) + h * HD;
    #pragma unroll
    for (int jb = 0; jb < 4; jb++)
        #pragma unroll
        for (int r = 0; r < 4; r++) {
            int row = lhi * 4 + r;
            attnb[obaseA + (size_t)row * (NH * HD) + jb * 16 + llo] =
                __float2bfloat16(accA[jb][r] * invA[r]);
            attnb[obaseB + (size_t)row * (NH * HD) + jb * 16 + llo] =
                __float2bfloat16(accB[jb][r] * invB[r]);
        }
}

// ---------------- launcher ----------------
extern "C" void kernel_launch(void* const* d_in, const int* in_sizes, int n_in,
                              void* d_out, int out_size, void* d_ws, size_t ws_size,
                              hipStream_t stream) {
    const float* x  = (const float*)d_in[0];
    const float* wq = (const float*)d_in[1];
    const float* wk = (const float*)d_in[2];
    const float* wv = (const float*)d_in[3];
    const float* wo = (const float*)d_in[4];
    float* out = (float*)d_out;

    char* ws = (char*)d_ws;
    size_t off = 0;
    auto alloc = [&](size_t bytes) { void* p = ws + off; off += (bytes + 255) & ~(size_t)255; return p; };
    bf16* xb   = (bf16*)alloc((size_t)M_TOT * HID * 2);
    bf16* wqb  = (bf16*)alloc((size_t)HID * HID * 2);
    bf16* wkb  = (bf16*)alloc((size_t)512 * HID * 2);
    bf16* wvb  = (bf16*)alloc((size_t)512 * HID * 2);
    bf16* wob  = (bf16*)alloc((size_t)HID * HID * 2);
    bf16* qb   = (bf16*)alloc((size_t)M_TOT * 2048 * 2);
    bf16* kb   = (bf16*)alloc((size_t)M_TOT * 512 * 2);
    bf16* vtb  = (bf16*)alloc((size_t)M_TOT * 512 * 2);
    bf16* attnb= (bf16*)alloc((size_t)M_TOT * 2048 * 2);
    float* cosb= (float*)alloc((size_t)S_LEN * 32 * 4);
    float* sinb= (float*)alloc((size_t)S_LEN * 32 * 4);

    auto cast = [&](const float* s, bf16* d, int n) {
        int n8 = n / 8;
        int grid = (n8 + 255) / 256;
        cast_kernel<<<grid, 256, 0, stream>>>(s, d, n8);
    };
    cast(x,  xb,  M_TOT * HID);
    cast(wq, wqb, HID * HID);
    cast(wk, wkb, 512 * HID);
    cast(wv, wvb, 512 * HID);
    cast(wo, wob, HID * HID);

    rope_tables_kernel<<<(S_LEN * 32 + 255) / 256, 256, 0, stream>>>(cosb, sinb);

    gemm_qkv_kernel<<<dim3(M_TOT / 128, 24), 256, 0, stream>>>(xb, wqb, wkb, wvb, qb, kb, vtb);

    {   // RoPE q
        int npairs = M_TOT * NH * 32;
        rope_kernel<<<(npairs + 255) / 256, 256, 0, stream>>>(qb, cosb, sinb, NH, npairs);
    }
    {   // RoPE k
        int npairs = M_TOT * NKV * 32;
        rope_kernel<<<(npairs + 255) / 256, 256, 0, stream>>>(kb, cosb, sinb, NKV, npairs);
    }

    flash_kernel<<<dim3(16, BATCH * NH), 256, 0, stream>>>(qb, kb, vtb, attnb);

    gemm_out_kernel<<<dim3(M_TOT / 128, HID / 128), 256, 0, stream>>>(attnb, wob, out);
}

// Round 5
// 250.592 us; speedup vs baseline: 1.6692x; 1.6692x over previous
//
#include <hip/hip_runtime.h>
#include <hip/hip_bf16.h>

typedef __hip_bfloat16 bf16;
typedef __attribute__((ext_vector_type(8))) short short8;
typedef __attribute__((ext_vector_type(4))) float f32x4;

#define S_LEN 2048
#define BATCH 2
#define M_TOT 4096   // BATCH*S_LEN
#define HID 2048
#define NH 32
#define NKV 8
#define HD 64
#define KVD 512      // NKV*HD
#define PSTR 72      // P-tile LDS stride (bf16)

#define MFMA16(a, b, c) __builtin_amdgcn_mfma_f32_16x16x32_bf16(a, b, c, 0, 0, 0)

__device__ __forceinline__ void gload_lds16(const bf16* g, bf16* l) {
    __builtin_amdgcn_global_load_lds((const __attribute__((address_space(1))) void*)g,
                                     (__attribute__((address_space(3))) void*)l,
                                     16, 0, 0);
}

// ---------------- cast fp32 -> bf16, vectorized ----------------
__global__ void cast_kernel(const float* __restrict__ src, bf16* __restrict__ dst, int n8) {
    int stride = gridDim.x * blockDim.x;
    for (int i = blockIdx.x * blockDim.x + threadIdx.x; i < n8; i += stride) {
        const float4* s = (const float4*)(src + (size_t)i * 8);
        float4 a = s[0], b = s[1];
        bf16 tmp[8];
        tmp[0] = __float2bfloat16(a.x); tmp[1] = __float2bfloat16(a.y);
        tmp[2] = __float2bfloat16(a.z); tmp[3] = __float2bfloat16(a.w);
        tmp[4] = __float2bfloat16(b.x); tmp[5] = __float2bfloat16(b.y);
        tmp[6] = __float2bfloat16(b.z); tmp[7] = __float2bfloat16(b.w);
        *(short8*)(dst + (size_t)i * 8) = *(short8*)tmp;
    }
}

// ---------------- RoPE tables: [S][32] cos, sin (fp32) ----------------
__global__ void rope_tables_kernel(float* __restrict__ cosb, float* __restrict__ sinb) {
    int idx = blockIdx.x * blockDim.x + threadIdx.x;
    if (idx >= S_LEN * 32) return;
    int s = idx >> 5, d = idx & 31;
    float freq = powf(10000.0f, -(float)(2 * d) / 64.0f);
    float ang = (float)s * freq;
    cosb[idx] = cosf(ang);
    sinb[idx] = sinf(ang);
}

// ---------------- RoPE apply, in place on bf16 (M_TOT, nh*64) ----------------
__global__ void rope_kernel(bf16* __restrict__ buf, const float* __restrict__ cosb,
                            const float* __restrict__ sinb, int nh, int npairs) {
    int stride = gridDim.x * blockDim.x;
    int hw = nh * 32;
    for (int idx = blockIdx.x * blockDim.x + threadIdx.x; idx < npairs; idx += stride) {
        int m = idx / hw;
        int r = idx - m * hw;
        int h = r >> 5, d = r & 31;
        int s = m & (S_LEN - 1);
        float c = cosb[s * 32 + d], sn = sinb[s * 32 + d];
        bf16* p = buf + (size_t)m * (nh * HD) + h * HD + 2 * d;
        __hip_bfloat162 xv = *(__hip_bfloat162*)p;
        float xe = __bfloat162float(xv.x), xo = __bfloat162float(xv.y);
        __hip_bfloat162 ov;
        ov.x = __float2bfloat16(xe * c - xo * sn);
        ov.y = __float2bfloat16(xe * sn + xo * c);
        *(__hip_bfloat162*)p = ov;
    }
}

// ---------------- GEMM core: 128x128 tile, BK=64, swizzled LDS (m97 class) ----
__device__ __forceinline__ void gemm_core(const bf16* __restrict__ A,
                                          const bf16* __restrict__ W,
                                          int K, int m0, int n0,
                                          bf16* As, bf16* Bs,
                                          f32x4 acc[4][4]) {
    int tid = threadIdx.x;
    int lane = tid & 63, wid = tid >> 6;
    int wr = wid >> 1, wc = wid & 1;
    int lhi = lane >> 4, llo = lane & 15;
    const bf16* gA[4]; const bf16* gB[4];
    bf16 *lA[4], *lB[4];
    #pragma unroll
    for (int q = 0; q < 4; q++) {
        int c = tid + 256 * q;
        int row = c >> 3;
        int sl = (c & 7) ^ (row & 7);     // pre-swizzled source slot
        gA[q] = A + (size_t)(m0 + row) * K + sl * 8;
        gB[q] = W + (size_t)(n0 + row) * K + sl * 8;
        lA[q] = As + c * 8;
        lB[q] = Bs + c * 8;
    }
    for (int k0 = 0; k0 < K; k0 += 64) {
        #pragma unroll
        for (int q = 0; q < 4; q++) {
            gload_lds16(gA[q] + k0, lA[q]);
            gload_lds16(gB[q] + k0, lB[q]);
        }
        __syncthreads();
        short8 af[4][2], bfr[4][2];
        #pragma unroll
        for (int i = 0; i < 4; i++) {
            int row = wr * 64 + i * 16 + llo;
            int x = row & 7;
            af[i][0] = *(const short8*)(As + row * 64 + ((lhi ^ x) * 8));
            af[i][1] = *(const short8*)(As + row * 64 + (((4 + lhi) ^ x) * 8));
        }
        #pragma unroll
        for (int j = 0; j < 4; j++) {
            int row = wc * 64 + j * 16 + llo;
            int x = row & 7;
            bfr[j][0] = *(const short8*)(Bs + row * 64 + ((lhi ^ x) * 8));
            bfr[j][1] = *(const short8*)(Bs + row * 64 + (((4 + lhi) ^ x) * 8));
        }
        #pragma unroll
        for (int i = 0; i < 4; i++)
            #pragma unroll
            for (int j = 0; j < 4; j++) {
                acc[i][j] = MFMA16(af[i][0], bfr[j][0], acc[i][j]);
                acc[i][j] = MFMA16(af[i][1], bfr[j][1], acc[i][j]);
            }
        __syncthreads();
    }
}

// ---------------- fused QKV projection ----------------
__global__ __launch_bounds__(256) void gemm_qkv_kernel(
        const bf16* __restrict__ xb,
        const bf16* __restrict__ wq, const bf16* __restrict__ wk, const bf16* __restrict__ wv,
        bf16* __restrict__ qb, bf16* __restrict__ kb, bf16* __restrict__ vtb) {
    __shared__ bf16 As[128 * 64];
    __shared__ bf16 Bs[128 * 64];
    int by = blockIdx.y;
    const bf16* W; bf16* Cb; int n0, ldc, mode;
    if (by < 16)      { W = wq; Cb = qb;  n0 = by * 128;        ldc = 2048; mode = 0; }
    else if (by < 20) { W = wk; Cb = kb;  n0 = (by - 16) * 128; ldc = 512;  mode = 0; }
    else              { W = wv; Cb = vtb; n0 = (by - 20) * 128; ldc = 0;    mode = 1; }
    int m0 = blockIdx.x * 128;

    f32x4 acc[4][4] = {};
    gemm_core(xb, W, HID, m0, n0, As, Bs, acc);

    int lane = threadIdx.x & 63, wid = threadIdx.x >> 6;
    int wr = wid >> 1, wc = wid & 1;
    int lhi = lane >> 4, llo = lane & 15;
    #pragma unroll
    for (int i = 0; i < 4; i++)
        #pragma unroll
        for (int j = 0; j < 4; j++) {
            int col = wc * 64 + j * 16 + llo;
            #pragma unroll
            for (int r = 0; r < 4; r++) {
                int row = wr * 64 + i * 16 + lhi * 4 + r;
                int m = m0 + row;
                float v = acc[i][j][r];
                if (mode == 0) {
                    Cb[(size_t)m * ldc + n0 + col] = __float2bfloat16(v);
                } else {
                    int bb = m >> 11, ss = m & 2047;
                    Cb[((size_t)(bb * 512 + n0 + col)) * S_LEN + ss] = __float2bfloat16(v);
                }
            }
        }
}

// ---------------- output projection: fp32 out ----------------
__global__ __launch_bounds__(256) void gemm_out_kernel(
        const bf16* __restrict__ attnb, const bf16* __restrict__ wob,
        float* __restrict__ out) {
    __shared__ bf16 As[128 * 64];
    __shared__ bf16 Bs[128 * 64];
    int m0 = blockIdx.x * 128;
    int n0 = blockIdx.y * 128;
    f32x4 acc[4][4] = {};
    gemm_core(attnb, wob, HID, m0, n0, As, Bs, acc);

    int lane = threadIdx.x & 63, wid = threadIdx.x >> 6;
    int wr = wid >> 1, wc = wid & 1;
    int lhi = lane >> 4, llo = lane & 15;
    #pragma unroll
    for (int i = 0; i < 4; i++)
        #pragma unroll
        for (int j = 0; j < 4; j++) {
            int col = wc * 64 + j * 16 + llo;
            #pragma unroll
            for (int r = 0; r < 4; r++) {
                int row = wr * 64 + i * 16 + lhi * 4 + r;
                out[(size_t)(m0 + row) * HID + n0 + col] = acc[i][j][r];
            }
        }
}

// ---------------- flash attention: softmax + PV for one 16x64 wave-update ----
template<bool MASKED>
__device__ __forceinline__ void sm_pv(const f32x4 z[4], int t0, int q0w, int lhi, int llo,
                                      bf16* pl, const short8 vf0[4], const short8 vf1[4],
                                      f32x4 acc[4], float psum[4]) {
    #pragma unroll
    for (int cb = 0; cb < 4; cb++)
        #pragma unroll
        for (int r = 0; r < 4; r++) {
            float p = __expf(z[cb][r] * 0.125f);
            if (MASKED)
                p = (t0 + cb * 16 + llo <= q0w + lhi * 4 + r) ? p : 0.f;
            psum[r] += p;
            pl[(lhi * 4 + r) * PSTR + cb * 16 + llo] = __float2bfloat16(p);
        }
    short8 p0 = *(const short8*)(pl + llo * PSTR + lhi * 8);
    short8 p1 = *(const short8*)(pl + llo * PSTR + 32 + lhi * 8);
    #pragma unroll
    for (int jb = 0; jb < 4; jb++) {
        acc[jb] = MFMA16(p0, vf0[jb], acc[jb]);
        acc[jb] = MFMA16(p1, vf1[jb], acc[jb]);
    }
}

// grid: (16, B*NH). Block i: q-tiles jA=i, jB=31-i; kv tiles 0..jB staged once.
// Double-buffered LDS K/V via global_load_lds; 2-phase schedule:
//   stage(buf^1, t+1) || compute(buf); vmcnt(0); barrier.
__global__ __launch_bounds__(256, 4) void flash_kernel(
        const bf16* __restrict__ qb, const bf16* __restrict__ kb,
        const bf16* __restrict__ vtb, bf16* __restrict__ attnb) {
    __shared__ bf16 Ks[2][64 * 64];
    __shared__ bf16 Vs[2][64 * 64];
    __shared__ bf16 Pl[4][2][16 * PSTR];
    int bh = blockIdx.y;
    int b = bh >> 5, h = bh & 31;
    int kvh = h >> 2;
    int jA = blockIdx.x, jB = 31 - jA;
    int tid = threadIdx.x;
    int wid = tid >> 6, lane = tid & 63;
    int lhi = lane >> 4, llo = lane & 15;
    int qA0 = jA * 64 + wid * 16;
    int qB0 = jB * 64 + wid * 16;

    const bf16* qbase = qb + (size_t)(b * S_LEN) * (NH * HD) + h * HD;
    short8 qfA0 = *(const short8*)(qbase + (size_t)(qA0 + llo) * (NH * HD) + lhi * 8);
    short8 qfA1 = *(const short8*)(qbase + (size_t)(qA0 + llo) * (NH * HD) + 32 + lhi * 8);
    short8 qfB0 = *(const short8*)(qbase + (size_t)(qB0 + llo) * (NH * HD) + lhi * 8);
    short8 qfB1 = *(const short8*)(qbase + (size_t)(qB0 + llo) * (NH * HD) + 32 + lhi * 8);

    const bf16* Kg = kb + (size_t)(b * S_LEN) * KVD + kvh * HD;
    const bf16* Vg = vtb + (size_t)(b * 512 + kvh * 64) * S_LEN;

    // staging: chunk c -> row c>>3; global slot pre-swizzled (c&7)^(row&7); LDS linear
    int c0 = tid, c1 = tid + 256;
    int r0 = c0 >> 3, s0 = ((c0 & 7) ^ (r0 & 7)) * 8;
    int r1 = c1 >> 3, s1 = ((c1 & 7) ^ (r1 & 7)) * 8;

    f32x4 accA[4] = {}, accB[4] = {};
    float psumA[4] = {0.f, 0.f, 0.f, 0.f}, psumB[4] = {0.f, 0.f, 0.f, 0.f};
    bf16* plA = &Pl[wid][0][0];
    bf16* plB = &Pl[wid][1][0];

    auto stage = [&](int buf, int t0) {
        gload_lds16(Kg + (size_t)(t0 + r0) * KVD + s0, &Ks[buf][c0 * 8]);
        gload_lds16(Kg + (size_t)(t0 + r1) * KVD + s1, &Ks[buf][c1 * 8]);
        gload_lds16(Vg + (size_t)r0 * S_LEN + t0 + s0, &Vs[buf][c0 * 8]);
        gload_lds16(Vg + (size_t)r1 * S_LEN + t0 + s1, &Vs[buf][c1 * 8]);
    };

    // prologue: stage tile 0, drain, barrier
    stage(0, 0);
    asm volatile("s_waitcnt vmcnt(0)" ::: "memory");
    __builtin_amdgcn_s_barrier();

    int cur = 0;
    for (int t = 0; t <= jB; ++t) {
        int t0 = t * 64;
        if (t < jB) stage(cur ^ 1, t0 + 64);   // async: lands during compute

        const bf16* Kc = &Ks[cur][0];
        const bf16* Vc = &Vs[cur][0];
        bool doA = (t <= jA);
        // ---- K frags + QK^T for both q-tiles ----
        f32x4 zA[4], zB[4];
        #pragma unroll
        for (int cb = 0; cb < 4; cb++) {
            int row = cb * 16 + llo;
            int x = row & 7;
            short8 k0 = *(const short8*)(Kc + row * 64 + ((lhi ^ x) * 8));
            short8 k1 = *(const short8*)(Kc + row * 64 + (((lhi + 4) ^ x) * 8));
            f32x4 z = {0.f, 0.f, 0.f, 0.f};
            z = MFMA16(qfB0, k0, z);
            z = MFMA16(qfB1, k1, z);
            zB[cb] = z;
            if (doA) {
                f32x4 y = {0.f, 0.f, 0.f, 0.f};
                y = MFMA16(qfA0, k0, y);
                y = MFMA16(qfA1, k1, y);
                zA[cb] = y;
            }
        }
        // ---- V frags (shared by A and B) ----
        short8 vf0[4], vf1[4];
        #pragma unroll
        for (int jb = 0; jb < 4; jb++) {
            int row = jb * 16 + llo;
            int x = row & 7;
            vf0[jb] = *(const short8*)(Vc + row * 64 + ((lhi ^ x) * 8));
            vf1[jb] = *(const short8*)(Vc + row * 64 + (((lhi + 4) ^ x) * 8));
        }
        // ---- softmax + PV (mask only on diagonal tiles; wave-uniform) ----
        if (t == jB) sm_pv<true >(zB, t0, qB0, lhi, llo, plB, vf0, vf1, accB, psumB);
        else         sm_pv<false>(zB, t0, qB0, lhi, llo, plB, vf0, vf1, accB, psumB);
        if (doA) {
            if (t == jA) sm_pv<true >(zA, t0, qA0, lhi, llo, plA, vf0, vf1, accA, psumA);
            else         sm_pv<false>(zA, t0, qA0, lhi, llo, plA, vf0, vf1, accA, psumA);
        }
        // drain this iter's staging loads (latency hidden by compute), then flip
        asm volatile("s_waitcnt vmcnt(0)" ::: "memory");
        __builtin_amdgcn_s_barrier();
        cur ^= 1;
    }

    // ---- final denominator reductions + epilogues ----
    #pragma unroll
    for (int off = 1; off < 16; off <<= 1)
        #pragma unroll
        for (int r = 0; r < 4; r++) {
            psumA[r] += __shfl_xor(psumA[r], off, 64);
            psumB[r] += __shfl_xor(psumB[r], off, 64);
        }
    float invA[4], invB[4];
    #pragma unroll
    for (int r = 0; r < 4; r++) {
        invA[r] = 1.0f / psumA[r];
        invB[r] = 1.0f / psumB[r];
    }
    size_t obaseA = ((size_t)(b * S_LEN) + qA0) * (NH * HD) + h * HD;
    size_t obaseB = ((size_t)(b * S_LEN) + qB0) * (NH * HD) + h * HD;
    #pragma unroll
    for (int jb = 0; jb < 4; jb++)
        #pragma unroll
        for (int r = 0; r < 4; r++) {
            int row = lhi * 4 + r;
            attnb[obaseA + (size_t)row * (NH * HD) + jb * 16 + llo] =
                __float2bfloat16(accA[jb][r] * invA[r]);
            attnb[obaseB + (size_t)row * (NH * HD) + jb * 16 + llo] =
                __float2bfloat16(accB[jb][r] * invB[r]);
        }
}

// ---------------- launcher ----------------
extern "C" void kernel_launch(void* const* d_in, const int* in_sizes, int n_in,
                              void* d_out, int out_size, void* d_ws, size_t ws_size,
                              hipStream_t stream) {
    const float* x  = (const float*)d_in[0];
    const float* wq = (const float*)d_in[1];
    const float* wk = (const float*)d_in[2];
    const float* wv = (const float*)d_in[3];
    const float* wo = (const float*)d_in[4];
    float* out = (float*)d_out;

    char* ws = (char*)d_ws;
    size_t off = 0;
    auto alloc = [&](size_t bytes) { void* p = ws + off; off += (bytes + 255) & ~(size_t)255; return p; };
    bf16* xb   = (bf16*)alloc((size_t)M_TOT * HID * 2);
    bf16* wqb  = (bf16*)alloc((size_t)HID * HID * 2);
    bf16* wkb  = (bf16*)alloc((size_t)512 * HID * 2);
    bf16* wvb  = (bf16*)alloc((size_t)512 * HID * 2);
    bf16* wob  = (bf16*)alloc((size_t)HID * HID * 2);
    bf16* qb   = (bf16*)alloc((size_t)M_TOT * 2048 * 2);
    bf16* kb   = (bf16*)alloc((size_t)M_TOT * 512 * 2);
    bf16* vtb  = (bf16*)alloc((size_t)M_TOT * 512 * 2);
    bf16* attnb= (bf16*)alloc((size_t)M_TOT * 2048 * 2);
    float* cosb= (float*)alloc((size_t)S_LEN * 32 * 4);
    float* sinb= (float*)alloc((size_t)S_LEN * 32 * 4);

    auto cast = [&](const float* s, bf16* d, int n) {
        int n8 = n / 8;
        int grid = (n8 + 255) / 256;
        cast_kernel<<<grid, 256, 0, stream>>>(s, d, n8);
    };
    cast(x,  xb,  M_TOT * HID);
    cast(wq, wqb, HID * HID);
    cast(wk, wkb, 512 * HID);
    cast(wv, wvb, 512 * HID);
    cast(wo, wob, HID * HID);

    rope_tables_kernel<<<(S_LEN * 32 + 255) / 256, 256, 0, stream>>>(cosb, sinb);

    gemm_qkv_kernel<<<dim3(M_TOT / 128, 24), 256, 0, stream>>>(xb, wqb, wkb, wvb, qb, kb, vtb);

    {   // RoPE q
        int npairs = M_TOT * NH * 32;
        rope_kernel<<<(npairs + 255) / 256, 256, 0, stream>>>(qb, cosb, sinb, NH, npairs);
    }
    {   // RoPE k
        int npairs = M_TOT * NKV * 32;
        rope_kernel<<<(npairs + 255) / 256, 256, 0, stream>>>(kb, cosb, sinb, NKV, npairs);
    }

    flash_kernel<<<dim3(16, BATCH * NH), 256, 0, stream>>>(qb, kb, vtb, attnb);

    gemm_out_kernel<<<dim3(M_TOT / 128, HID / 128), 256, 0, stream>>>(attnb, wob, out);
}

// Round 6
// 211.933 us; speedup vs baseline: 1.9736x; 1.1824x over previous
//
#include <hip/hip_runtime.h>
#include <hip/hip_bf16.h>

typedef __hip_bfloat16 bf16;
typedef __attribute__((ext_vector_type(8))) short short8;
typedef __attribute__((ext_vector_type(4))) float f32x4;

#define S_LEN 2048
#define BATCH 2
#define M_TOT 4096   // BATCH*S_LEN
#define HID 2048
#define NH 32
#define NKV 8
#define HD 64
#define KVD 512      // NKV*HD

#define MFMA16(a, b, c) __builtin_amdgcn_mfma_f32_16x16x32_bf16(a, b, c, 0, 0, 0)

__device__ __forceinline__ void gload_lds16(const bf16* g, bf16* l) {
    __builtin_amdgcn_global_load_lds((const __attribute__((address_space(1))) void*)g,
                                     (__attribute__((address_space(3))) void*)l,
                                     16, 0, 0);
}

__device__ __forceinline__ float b2f(short v) {
    unsigned u = ((unsigned)(unsigned short)v) << 16;
    float f; __builtin_memcpy(&f, &u, 4); return f;
}

// ---------------- cast fp32 -> bf16, vectorized ----------------
__global__ void cast_kernel(const float* __restrict__ src, bf16* __restrict__ dst, int n8) {
    int stride = gridDim.x * blockDim.x;
    for (int i = blockIdx.x * blockDim.x + threadIdx.x; i < n8; i += stride) {
        const float4* s = (const float4*)(src + (size_t)i * 8);
        float4 a = s[0], b = s[1];
        bf16 tmp[8];
        tmp[0] = __float2bfloat16(a.x); tmp[1] = __float2bfloat16(a.y);
        tmp[2] = __float2bfloat16(a.z); tmp[3] = __float2bfloat16(a.w);
        tmp[4] = __float2bfloat16(b.x); tmp[5] = __float2bfloat16(b.y);
        tmp[6] = __float2bfloat16(b.z); tmp[7] = __float2bfloat16(b.w);
        *(short8*)(dst + (size_t)i * 8) = *(short8*)tmp;
    }
}

// ---------------- RoPE tables: [S][32] cos, sin (fp32) ----------------
__global__ void rope_tables_kernel(float* __restrict__ cosb, float* __restrict__ sinb) {
    int idx = blockIdx.x * blockDim.x + threadIdx.x;
    if (idx >= S_LEN * 32) return;
    int s = idx >> 5, d = idx & 31;
    float freq = powf(10000.0f, -(float)(2 * d) / 64.0f);
    float ang = (float)s * freq;
    cosb[idx] = cosf(ang);
    sinb[idx] = sinf(ang);
}

// ---------------- RoPE apply, in place on bf16 (k only now) ----------------
__global__ void rope_kernel(bf16* __restrict__ buf, const float* __restrict__ cosb,
                            const float* __restrict__ sinb, int nh, int npairs) {
    int stride = gridDim.x * blockDim.x;
    int hw = nh * 32;
    for (int idx = blockIdx.x * blockDim.x + threadIdx.x; idx < npairs; idx += stride) {
        int m = idx / hw;
        int r = idx - m * hw;
        int h = r >> 5, d = r & 31;
        int s = m & (S_LEN - 1);
        float c = cosb[s * 32 + d], sn = sinb[s * 32 + d];
        bf16* p = buf + (size_t)m * (nh * HD) + h * HD + 2 * d;
        __hip_bfloat162 xv = *(__hip_bfloat162*)p;
        float xe = __bfloat162float(xv.x), xo = __bfloat162float(xv.y);
        __hip_bfloat162 ov;
        ov.x = __float2bfloat16(xe * c - xo * sn);
        ov.y = __float2bfloat16(xe * sn + xo * c);
        *(__hip_bfloat162*)p = ov;
    }
}

// rope one 8-elem Q fragment (4 even/odd pairs) with 1/8 scale folded in (exact)
__device__ __forceinline__ short8 rope8(short8 v, float4 c, float4 s) {
    short8 o;
    const float* cp = (const float*)&c;
    const float* sp = (const float*)&s;
    #pragma unroll
    for (int m = 0; m < 4; m++) {
        float xe = b2f(v[2 * m]) * 0.125f;
        float xo = b2f(v[2 * m + 1]) * 0.125f;
        bf16 oe = __float2bfloat16(xe * cp[m] - xo * sp[m]);
        bf16 oo = __float2bfloat16(xe * sp[m] + xo * cp[m]);
        short se, so;
        __builtin_memcpy(&se, &oe, 2); __builtin_memcpy(&so, &oo, 2);
        o[2 * m] = se; o[2 * m + 1] = so;
    }
    return o;
}

// ---------------- GEMM core: 128x128 tile, BK=64, swizzled LDS ----------------
__device__ __forceinline__ void gemm_core(const bf16* __restrict__ A,
                                          const bf16* __restrict__ W,
                                          int K, int m0, int n0,
                                          bf16* As, bf16* Bs,
                                          f32x4 acc[4][4]) {
    int tid = threadIdx.x;
    int lane = tid & 63, wid = tid >> 6;
    int wr = wid >> 1, wc = wid & 1;
    int lhi = lane >> 4, llo = lane & 15;
    const bf16* gA[4]; const bf16* gB[4];
    bf16 *lA[4], *lB[4];
    #pragma unroll
    for (int q = 0; q < 4; q++) {
        int c = tid + 256 * q;
        int row = c >> 3;
        int sl = (c & 7) ^ (row & 7);     // pre-swizzled source slot
        gA[q] = A + (size_t)(m0 + row) * K + sl * 8;
        gB[q] = W + (size_t)(n0 + row) * K + sl * 8;
        lA[q] = As + c * 8;
        lB[q] = Bs + c * 8;
    }
    for (int k0 = 0; k0 < K; k0 += 64) {
        #pragma unroll
        for (int q = 0; q < 4; q++) {
            gload_lds16(gA[q] + k0, lA[q]);
            gload_lds16(gB[q] + k0, lB[q]);
        }
        __syncthreads();
        short8 af[4][2], bfr[4][2];
        #pragma unroll
        for (int i = 0; i < 4; i++) {
            int row = wr * 64 + i * 16 + llo;
            int x = row & 7;
            af[i][0] = *(const short8*)(As + row * 64 + ((lhi ^ x) * 8));
            af[i][1] = *(const short8*)(As + row * 64 + (((4 + lhi) ^ x) * 8));
        }
        #pragma unroll
        for (int j = 0; j < 4; j++) {
            int row = wc * 64 + j * 16 + llo;
            int x = row & 7;
            bfr[j][0] = *(const short8*)(Bs + row * 64 + ((lhi ^ x) * 8));
            bfr[j][1] = *(const short8*)(Bs + row * 64 + (((4 + lhi) ^ x) * 8));
        }
        #pragma unroll
        for (int i = 0; i < 4; i++)
            #pragma unroll
            for (int j = 0; j < 4; j++) {
                acc[i][j] = MFMA16(af[i][0], bfr[j][0], acc[i][j]);
                acc[i][j] = MFMA16(af[i][1], bfr[j][1], acc[i][j]);
            }
        __syncthreads();
    }
}

// ---------------- fused QKV projection ----------------
__global__ __launch_bounds__(256) void gemm_qkv_kernel(
        const bf16* __restrict__ xb,
        const bf16* __restrict__ wq, const bf16* __restrict__ wk, const bf16* __restrict__ wv,
        bf16* __restrict__ qb, bf16* __restrict__ kb, bf16* __restrict__ vtb) {
    __shared__ bf16 As[128 * 64];
    __shared__ bf16 Bs[128 * 64];
    int by = blockIdx.y;
    const bf16* W; bf16* Cb; int n0, ldc, mode;
    if (by < 16)      { W = wq; Cb = qb;  n0 = by * 128;        ldc = 2048; mode = 0; }
    else if (by < 20) { W = wk; Cb = kb;  n0 = (by - 16) * 128; ldc = 512;  mode = 0; }
    else              { W = wv; Cb = vtb; n0 = (by - 20) * 128; ldc = 0;    mode = 1; }
    int m0 = blockIdx.x * 128;

    f32x4 acc[4][4] = {};
    gemm_core(xb, W, HID, m0, n0, As, Bs, acc);

    int lane = threadIdx.x & 63, wid = threadIdx.x >> 6;
    int wr = wid >> 1, wc = wid & 1;
    int lhi = lane >> 4, llo = lane & 15;
    #pragma unroll
    for (int i = 0; i < 4; i++)
        #pragma unroll
        for (int j = 0; j < 4; j++) {
            int col = wc * 64 + j * 16 + llo;
            #pragma unroll
            for (int r = 0; r < 4; r++) {
                int row = wr * 64 + i * 16 + lhi * 4 + r;
                int m = m0 + row;
                float v = acc[i][j][r];
                if (mode == 0) {
                    Cb[(size_t)m * ldc + n0 + col] = __float2bfloat16(v);
                } else {
                    int bb = m >> 11, ss = m & 2047;
                    Cb[((size_t)(bb * 512 + n0 + col)) * S_LEN + ss] = __float2bfloat16(v);
                }
            }
        }
}

// ---------------- output projection: fp32 out ----------------
__global__ __launch_bounds__(256) void gemm_out_kernel(
        const bf16* __restrict__ attnb, const bf16* __restrict__ wob,
        float* __restrict__ out) {
    __shared__ bf16 As[128 * 64];
    __shared__ bf16 Bs[128 * 64];
    int m0 = blockIdx.x * 128;
    int n0 = blockIdx.y * 128;
    f32x4 acc[4][4] = {};
    gemm_core(attnb, wob, HID, m0, n0, As, Bs, acc);

    int lane = threadIdx.x & 63, wid = threadIdx.x >> 6;
    int wr = wid >> 1, wc = wid & 1;
    int lhi = lane >> 4, llo = lane & 15;
    #pragma unroll
    for (int i = 0; i < 4; i++)
        #pragma unroll
        for (int j = 0; j < 4; j++) {
            int col = wc * 64 + j * 16 + llo;
            #pragma unroll
            for (int r = 0; r < 4; r++) {
                int row = wr * 64 + i * 16 + lhi * 4 + r;
                out[(size_t)(m0 + row) * HID + n0 + col] = acc[i][j][r];
            }
        }
}

// ---------------- flash attention: two uniform single-update phases ----------
// grid: (16, B*NH). Block i runs phase(jA=i) then phase(jB=31-i): 33 uniform
// iterations total per block; 1024 blocks = exactly 4/CU, all co-resident.
// K/V double-buffered LDS (global_load_lds, pre-swizzled source); P per-wave
// single buffer, stride-64 XOR swizzle. RoPE(q) + 1/8 scale fused into Q load.
__global__ __launch_bounds__(256, 4) void flash_kernel(
        const bf16* __restrict__ qb, const bf16* __restrict__ kb,
        const bf16* __restrict__ vtb, const float* __restrict__ cosb,
        const float* __restrict__ sinb, bf16* __restrict__ attnb) {
    __shared__ bf16 Ks[2][64 * 64];
    __shared__ bf16 Vs[2][64 * 64];
    __shared__ bf16 Pl[4][16 * 64];
    int bh = blockIdx.y;
    int b = bh >> 5, h = bh & 31;
    int kvh = h >> 2;
    int tid = threadIdx.x;
    int wid = tid >> 6, lane = tid & 63;
    int lhi = lane >> 4, llo = lane & 15;

    const bf16* Kg = kb + (size_t)(b * S_LEN) * KVD + kvh * HD;
    const bf16* Vg = vtb + (size_t)(b * 512 + kvh * 64) * S_LEN;

    int c0 = tid, c1 = tid + 256;
    int r0 = c0 >> 3, s0 = ((c0 & 7) ^ (r0 & 7)) * 8;
    int r1 = c1 >> 3, s1 = ((c1 & 7) ^ (r1 & 7)) * 8;

    bf16* pl = &Pl[wid][0];
    const int prd0 = llo * 64 + ((lhi ^ (llo & 7)) * 8);        // P read frag0
    const int prd1 = llo * 64 + (((lhi + 4) ^ (llo & 7)) * 8);  // P read frag1

    auto stage = [&](int buf, int t0) {
        gload_lds16(Kg + (size_t)(t0 + r0) * KVD + s0, &Ks[buf][c0 * 8]);
        gload_lds16(Kg + (size_t)(t0 + r1) * KVD + s1, &Ks[buf][c1 * 8]);
        gload_lds16(Vg + (size_t)r0 * S_LEN + t0 + s0, &Vs[buf][c0 * 8]);
        gload_lds16(Vg + (size_t)r1 * S_LEN + t0 + s1, &Vs[buf][c1 * 8]);
    };

    auto run_phase = [&](int j) {
        int qrow0 = j * 64 + wid * 16;
        int spos = qrow0 + llo;
        const bf16* qrow = qb + ((size_t)(b * S_LEN) + spos) * (NH * HD) + h * HD;
        float4 cv0 = *(const float4*)(cosb + spos * 32 + lhi * 4);
        float4 sv0 = *(const float4*)(sinb + spos * 32 + lhi * 4);
        float4 cv1 = *(const float4*)(cosb + spos * 32 + 16 + lhi * 4);
        float4 sv1 = *(const float4*)(sinb + spos * 32 + 16 + lhi * 4);
        short8 qf0 = rope8(*(const short8*)(qrow + lhi * 8), cv0, sv0);
        short8 qf1 = rope8(*(const short8*)(qrow + 32 + lhi * 8), cv1, sv1);

        f32x4 acc[4] = {};
        float psum[4] = {0.f, 0.f, 0.f, 0.f};

        stage(0, 0);
        asm volatile("s_waitcnt vmcnt(0)" ::: "memory");
        __builtin_amdgcn_s_barrier();
        int cur = 0;
        for (int t = 0; t <= j; ++t) {
            int t0 = t * 64;
            if (t < j) stage(cur ^ 1, t0 + 64);   // async: lands during compute
            const bf16* Kc = &Ks[cur][0];
            const bf16* Vc = &Vs[cur][0];
            // ---- QK^T ----
            f32x4 z[4];
            #pragma unroll
            for (int cb = 0; cb < 4; cb++) {
                int row = cb * 16 + llo;
                int x = row & 7;
                short8 k0 = *(const short8*)(Kc + row * 64 + ((lhi ^ x) * 8));
                short8 k1 = *(const short8*)(Kc + row * 64 + (((lhi + 4) ^ x) * 8));
                f32x4 zz = {0.f, 0.f, 0.f, 0.f};
                zz = MFMA16(qf0, k0, zz);
                zz = MFMA16(qf1, k1, zz);
                z[cb] = zz;
            }
            // ---- softmax + P write (mask only on diagonal tile) ----
            if (t == j) {
                #pragma unroll
                for (int cb = 0; cb < 4; cb++)
                    #pragma unroll
                    for (int r = 0; r < 4; r++) {
                        float p = __expf(z[cb][r]);
                        p = (t0 + cb * 16 + llo <= qrow0 + lhi * 4 + r) ? p : 0.f;
                        psum[r] += p;
                        int row = lhi * 4 + r;
                        pl[row * 64 + (((2 * cb + (llo >> 3)) ^ (row & 7)) * 8) + (llo & 7)]
                            = __float2bfloat16(p);
                    }
            } else {
                #pragma unroll
                for (int cb = 0; cb < 4; cb++)
                    #pragma unroll
                    for (int r = 0; r < 4; r++) {
                        float p = __expf(z[cb][r]);
                        psum[r] += p;
                        int row = lhi * 4 + r;
                        pl[row * 64 + (((2 * cb + (llo >> 3)) ^ (row & 7)) * 8) + (llo & 7)]
                            = __float2bfloat16(p);
                    }
            }
            // ---- P read + PV (V frags read here to shorten liveness) ----
            short8 pa0 = *(const short8*)(pl + prd0);
            short8 pa1 = *(const short8*)(pl + prd1);
            #pragma unroll
            for (int jb = 0; jb < 4; jb++) {
                int row = jb * 16 + llo;
                int x = row & 7;
                short8 v0 = *(const short8*)(Vc + row * 64 + ((lhi ^ x) * 8));
                short8 v1 = *(const short8*)(Vc + row * 64 + (((lhi + 4) ^ x) * 8));
                acc[jb] = MFMA16(pa0, v0, acc[jb]);
                acc[jb] = MFMA16(pa1, v1, acc[jb]);
            }
            asm volatile("s_waitcnt vmcnt(0)" ::: "memory");
            __builtin_amdgcn_s_barrier();
            cur ^= 1;
        }
        // ---- denominator reduce + epilogue ----
        #pragma unroll
        for (int off = 1; off < 16; off <<= 1)
            #pragma unroll
            for (int r = 0; r < 4; r++)
                psum[r] += __shfl_xor(psum[r], off, 64);
        float inv[4];
        #pragma unroll
        for (int r = 0; r < 4; r++) inv[r] = 1.0f / psum[r];
        size_t obase = ((size_t)(b * S_LEN) + qrow0) * (NH * HD) + h * HD;
        #pragma unroll
        for (int jb = 0; jb < 4; jb++)
            #pragma unroll
            for (int r = 0; r < 4; r++)
                attnb[obase + (size_t)(lhi * 4 + r) * (NH * HD) + jb * 16 + llo] =
                    __float2bfloat16(acc[jb][r] * inv[r]);
    };

    run_phase(blockIdx.x);
    run_phase(31 - blockIdx.x);
}

// ---------------- launcher ----------------
extern "C" void kernel_launch(void* const* d_in, const int* in_sizes, int n_in,
                              void* d_out, int out_size, void* d_ws, size_t ws_size,
                              hipStream_t stream) {
    const float* x  = (const float*)d_in[0];
    const float* wq = (const float*)d_in[1];
    const float* wk = (const float*)d_in[2];
    const float* wv = (const float*)d_in[3];
    const float* wo = (const float*)d_in[4];
    float* out = (float*)d_out;

    char* ws = (char*)d_ws;
    size_t off = 0;
    auto alloc = [&](size_t bytes) { void* p = ws + off; off += (bytes + 255) & ~(size_t)255; return p; };
    bf16* xb   = (bf16*)alloc((size_t)M_TOT * HID * 2);
    bf16* wqb  = (bf16*)alloc((size_t)HID * HID * 2);
    bf16* wkb  = (bf16*)alloc((size_t)512 * HID * 2);
    bf16* wvb  = (bf16*)alloc((size_t)512 * HID * 2);
    bf16* wob  = (bf16*)alloc((size_t)HID * HID * 2);
    bf16* qb   = (bf16*)alloc((size_t)M_TOT * 2048 * 2);
    bf16* kb   = (bf16*)alloc((size_t)M_TOT * 512 * 2);
    bf16* vtb  = (bf16*)alloc((size_t)M_TOT * 512 * 2);
    bf16* attnb= (bf16*)alloc((size_t)M_TOT * 2048 * 2);
    float* cosb= (float*)alloc((size_t)S_LEN * 32 * 4);
    float* sinb= (float*)alloc((size_t)S_LEN * 32 * 4);

    auto cast = [&](const float* s, bf16* d, int n) {
        int n8 = n / 8;
        int grid = (n8 + 255) / 256;
        cast_kernel<<<grid, 256, 0, stream>>>(s, d, n8);
    };
    cast(x,  xb,  M_TOT * HID);
    cast(wq, wqb, HID * HID);
    cast(wk, wkb, 512 * HID);
    cast(wv, wvb, 512 * HID);
    cast(wo, wob, HID * HID);

    rope_tables_kernel<<<(S_LEN * 32 + 255) / 256, 256, 0, stream>>>(cosb, sinb);

    gemm_qkv_kernel<<<dim3(M_TOT / 128, 24), 256, 0, stream>>>(xb, wqb, wkb, wvb, qb, kb, vtb);

    {   // RoPE k only (RoPE q fused into flash)
        int npairs = M_TOT * NKV * 32;
        rope_kernel<<<(npairs + 255) / 256, 256, 0, stream>>>(kb, cosb, sinb, NKV, npairs);
    }

    flash_kernel<<<dim3(16, BATCH * NH), 256, 0, stream>>>(qb, kb, vtb, cosb, sinb, attnb);

    gemm_out_kernel<<<dim3(M_TOT / 128, HID / 128), 256, 0, stream>>>(attnb, wob, out);
}